// Round 1
// baseline (208.968 us; speedup 1.0000x reference)
//
#include <hip/hip_runtime.h>
#include <hip/hip_bf16.h>
#include <math.h>

#define TPB 512
#define XS    132           // f32 X region el-stride (dwords); also epilogue scratch
#define OFF_X  0            // [64][132] f32: x -> attended -> down-out scratch; bytes [0,16384) reused as h_bf
#define OFF_XR 8448         // [64][68] dwords: xr (17-stride uint4), later att_bf [8i][64b][16n] bf16
#define XRU4   2112         // OFF_XR/4 : uint4 index of XR region
#define SMEM_FLOATS (8448 + 4352)       // 12800 dwords = 51200 B -> 3 blocks/CU
#define SMEM_BYTES  (SMEM_FLOATS * 4)

// ---- Cl(3,0): slot s (0..43) of the GP pair-sum (verified round 4) ----
constexpr int SCNT[44] = {1,1,1,1,1,1,1,1, 3,1,1,1, 2,2,2,2,2,2, 1,1,1, 3,
                          3, 2,2,2, 1,1,1,1,1,1, 2,2,2, 3, 1,1,1,1,1,1,1,1};
constexpr int T1I[44] = {0,0,0,0,0,0,0,0, 1,1,2,3, 2,1,1,1,1,2, 3,2,1, 1,
                         4, 4,4,5, 6,5,4,4,5,6, 5,4,4, 4, 7,7,7,7,7,7,7,7};
constexpr int T1K[44] = {0,1,2,3,4,5,6,7, 1,0,0,0, 4,4,5,2,3,3, 7,7,7, 6,
                         4, 2,1,1, 7,7,7,0,0,0, 6,6,5, 3, 7,6,5,4,3,2,1,0};
constexpr int T1S[44] = {1,1,1,1,1,1,1,1, 1,1,1,1, 0,1,1,1,1,1, 1,0,1, 1,
                         0, 1,0,0, 0,1,0,1,1,1, 0,1,0, 1, 0,0,1,0,1,0,1,1};
constexpr int T2I[44] = {0,0,0,0,0,0,0,0, 2,0,0,0, 3,3,2,2,3,3, 0,0,0, 2,
                         5, 5,6,6, 0,0,0,0,0,0, 6,6,5, 5, 0,0,0,0,0,0,0,0};
constexpr int T2K[44] = {0,0,0,0,0,0,0,0, 2,0,0,0, 5,6,6,1,1,2, 0,0,0, 5,
                         5, 3,3,2, 0,0,0,0,0,0, 5,4,4, 2, 0,0,0,0,0,0,0,0};
constexpr int T2S[44] = {1,1,1,1,1,1,1,1, 1,1,1,1, 0,0,1,0,0,0, 1,1,1, 0,
                         0, 1,1,0, 1,1,1,1,1,1, 1,0,1, 0, 1,1,1,1,1,1,1,1};
constexpr int T3I[44] = {0,0,0,0,0,0,0,0, 3,0,0,0, 0,0,0,0,0,0, 0,0,0, 3,
                         6, 0,0,0, 0,0,0,0,0,0, 0,0,0, 6, 0,0,0,0,0,0,0,0};
constexpr int T3K[44] = {0,0,0,0,0,0,0,0, 3,0,0,0, 0,0,0,0,0,0, 0,0,0, 4,
                         6, 0,0,0, 0,0,0,0,0,0, 0,0,0, 1, 0,0,0,0,0,0,0,0};
constexpr int T3S[44] = {1,1,1,1,1,1,1,1, 1,1,1,1, 1,1,1,1,1,1, 1,1,1, 1,
                         0, 1,1,1, 1,1,1,1,1,1, 1,1,1, 1, 1,1,1,1,1,1,1,1};
constexpr int CP[44] = {
    0, 1,1,1, 2,2,2, 3,
    4, 5,5,5, 6,6,6, 7,7,7, 8,8,8, 9,
    10, 11,11,11, 12,12,12, 13,13,13, 14,14,14, 15,
    16, 17,17,17, 18,18,18, 19};
constexpr int CJ[44] = {
    0, 1,2,3, 4,5,6, 7,
    0, 1,2,3, 1,2,3, 4,5,6, 4,5,6, 7,
    0, 1,2,3, 1,2,3, 4,5,6, 4,5,6, 7,
    0, 1,2,3, 4,5,6, 7};

typedef __attribute__((ext_vector_type(8))) short bf16x8;
typedef __attribute__((ext_vector_type(4))) float f32x4;
union U4B { uint4 u; bf16x8 h; };

__device__ __forceinline__ float sigmoidf_(float v) {
    return __builtin_amdgcn_rcpf(1.0f + __expf(-v));
}
__device__ __forceinline__ unsigned pk2(float lo, float hi) {
    __hip_bfloat162 h = __float22bfloat162_rn(make_float2(lo, hi));
    return *reinterpret_cast<unsigned*>(&h);
}
__device__ __forceinline__ unsigned short bfb(float v) {
    __hip_bfloat16 h = __float2bfloat16(v);
    return *reinterpret_cast<unsigned short*>(&h);
}
__device__ __forceinline__ uint4 pkrow(const float* v) {
    return make_uint4(pk2(v[0],v[1]), pk2(v[2],v[3]), pk2(v[4],v[5]), pk2(v[6],v[7]));
}
__device__ __forceinline__ void unpkrow(uint4 u, float* v) {
    v[0]=__uint_as_float(u.x<<16); v[1]=__uint_as_float(u.x&0xffff0000u);
    v[2]=__uint_as_float(u.y<<16); v[3]=__uint_as_float(u.y&0xffff0000u);
    v[4]=__uint_as_float(u.z<<16); v[5]=__uint_as_float(u.z&0xffff0000u);
    v[6]=__uint_as_float(u.w<<16); v[7]=__uint_as_float(u.w&0xffff0000u);
}

// ---- prep: pack w_up / w_down into B-fragment-ordered bf16 pairs ----
// frag f = ch*8 + i ; lane l ; dword jp ; k-slot map: k0 = 8*(l>>4) + 2*jp  (k>=16 -> 0)
// up:   B[k=n][col=m2=ch*16+(l&15)]  = w_up[m2][n][g(i)]
// down: B[k=m2loc][col=m=(l&15)]     = w_down[m][ch*16+m2loc][g(i)]
__global__ void prep_pack(const float* __restrict__ w_up,
                          const float* __restrict__ w_down,
                          unsigned* __restrict__ wsu,
                          unsigned* __restrict__ wsd)
{
    const int t = blockIdx.x * 256 + threadIdx.x;       // 0..16383
    const int d  = t & 8191;
    const int f  = d >> 8;                              // 0..31
    const int rj = d & 255;
    const int l  = rj >> 2, jp = rj & 3;
    const int ch = f >> 3, i = f & 7;
    const int g  = (i == 0) ? 0 : (i <= 3 ? 1 : (i <= 6 ? 2 : 3));
    const int k0 = ((l >> 4) << 3) + (jp << 1);
    if (t < 8192) {
        const int m2 = (ch << 4) + (l & 15);
        const float v0 = (k0     < 16) ? w_up[(m2*16 + k0    )*4 + g] : 0.f;
        const float v1 = (k0 + 1 < 16) ? w_up[(m2*16 + k0 + 1)*4 + g] : 0.f;
        wsu[d] = pk2(v0, v1);
    } else {
        const int m = l & 15;
        const float v0 = (k0     < 16) ? w_down[(m*64 + (ch<<4) + k0    )*4 + g] : 0.f;
        const float v1 = (k0 + 1 < 16) ? w_down[(m*64 + (ch<<4) + k0 + 1)*4 + g] : 0.f;
        wsd[d] = pk2(v0, v1);
    }
}

__global__ __launch_bounds__(TPB, 6)
void mv_block_kernel(const float* __restrict__ xg,
                     const float* __restrict__ w_right,
                     const float* __restrict__ a_norm,
                     const float* __restrict__ w_gp,
                     const float* __restrict__ w_left,
                     const float* __restrict__ b_left,
                     const float* __restrict__ w_up,
                     const float* __restrict__ b_up,
                     const float* __restrict__ a_act,
                     const float* __restrict__ b_act,
                     const float* __restrict__ w_down,
                     const float* __restrict__ b_down,
                     const uint4* __restrict__ wsu,
                     const uint4* __restrict__ wsd,
                     float* __restrict__ outg)
{
    extern __shared__ float sm[];
    uint4* uXR = ((uint4*)sm) + XRU4;
    const int t = threadIdx.x;
    const int b = t & 63;                                   // lane = batch element (A-C) / MFMA lane (D)
    const int w = __builtin_amdgcn_readfirstlane(t >> 6);   // wave 0..7 (uniform)
    const int mA = w, mB = w + 8;                           // two channels per wave
    const int g = blockIdx.x;

    // ---------- stage x (coalesced, f32) ----------
    {
        const float4* xs = (const float4*)xg + (size_t)g * 2048;
        #pragma unroll
        for (int r = 0; r < 4; ++r) {
            const int idx = r * TPB + t;
            const float4 v = xs[idx];
            const int el = idx >> 5, off = idx & 31;
            *(float4*)&sm[OFF_X + el * XS + off * 4] = v;
        }
    }
    __syncthreads();

    // ---------- phase A: right-linear + left-linear (2 channels, weights in SGPRs) ----------
    float xrA[8] = {0,0,0,0,0,0,0,0}, xrB[8] = {0,0,0,0,0,0,0,0};
    float lfA[8] = {0,0,0,0,0,0,0,0}, lfB[8] = {0,0,0,0,0,0,0,0};
    {
        const float* sx = &sm[OFF_X + b * XS];
        #pragma unroll 1
        for (int n = 0; n < 16; ++n) {
            const float4 xa = *(const float4*)&sx[n*8];
            const float4 xb = *(const float4*)&sx[n*8+4];
            const float4 wa = *(const float4*)&w_right[(mA*16+n)*4];
            const float4 wb = *(const float4*)&w_right[(mB*16+n)*4];
            const float4 va = *(const float4*)&w_left [(mA*16+n)*4];
            const float4 vb = *(const float4*)&w_left [(mB*16+n)*4];
            xrA[0]+=xa.x*wa.x; xrA[1]+=xa.y*wa.y; xrA[2]+=xa.z*wa.y; xrA[3]+=xa.w*wa.y;
            xrA[4]+=xb.x*wa.z; xrA[5]+=xb.y*wa.z; xrA[6]+=xb.z*wa.z; xrA[7]+=xb.w*wa.w;
            xrB[0]+=xa.x*wb.x; xrB[1]+=xa.y*wb.y; xrB[2]+=xa.z*wb.y; xrB[3]+=xa.w*wb.y;
            xrB[4]+=xb.x*wb.z; xrB[5]+=xb.y*wb.z; xrB[6]+=xb.z*wb.z; xrB[7]+=xb.w*wb.w;
            lfA[0]+=xa.x*va.x; lfA[1]+=xa.y*va.y; lfA[2]+=xa.z*va.y; lfA[3]+=xa.w*va.y;
            lfA[4]+=xb.x*va.z; lfA[5]+=xb.y*va.z; lfA[6]+=xb.z*va.z; lfA[7]+=xb.w*va.w;
            lfB[0]+=xa.x*vb.x; lfB[1]+=xa.y*vb.y; lfB[2]+=xa.z*vb.y; lfB[3]+=xa.w*vb.y;
            lfB[4]+=xb.x*vb.z; lfB[5]+=xb.y*vb.z; lfB[6]+=xb.z*vb.z; lfB[7]+=xb.w*vb.w;
        }
    }

    // ---------- phase B: gated per-grade normalization ----------
    #pragma unroll
    for (int q = 0; q < 2; ++q) {
        float* xr = q ? xrB : xrA;
        const int m = q ? mB : mA;
        const float q0 = xr[0]*xr[0];
        const float q1 = xr[1]*xr[1] + xr[2]*xr[2] + xr[3]*xr[3];
        const float q2 = xr[4]*xr[4] + xr[5]*xr[5] + xr[6]*xr[6];
        const float q3 = xr[7]*xr[7];
        const float4 an = *(const float4*)&a_norm[m*4];
        const float i0 = __builtin_amdgcn_rcpf(sigmoidf_(an.x)*(sqrtf(q0)-1.0f)+1.0f + 1e-6f);
        const float i1 = __builtin_amdgcn_rcpf(sigmoidf_(an.y)*(sqrtf(q1)-1.0f)+1.0f + 1e-6f);
        const float i2 = __builtin_amdgcn_rcpf(sigmoidf_(an.z)*(sqrtf(q2)-1.0f)+1.0f + 1e-6f);
        const float i3 = __builtin_amdgcn_rcpf(sigmoidf_(an.w)*(sqrtf(q3)-1.0f)+1.0f + 1e-6f);
        xr[0]*=i0; xr[1]*=i1; xr[2]*=i1; xr[3]*=i1;
        xr[4]*=i2; xr[5]*=i2; xr[6]*=i2; xr[7]*=i3;
    }
    uXR[b*17 + mA] = pkrow(xrA);     // xr -> bf16 LDS (1 uint4 per channel)
    uXR[b*17 + mB] = pkrow(xrB);
    __syncthreads();

    // ---------- phase C: direct GP; pair products shared across the wave's 2 channels ----------
    float gpA[8] = {0,0,0,0,0,0,0,0}, gpB[8] = {0,0,0,0,0,0,0,0};
    {
        #pragma unroll 1
        for (int n = 0; n < 16; ++n) {
            float xv[8], rv[8];
            { const float4 u = *(const float4*)&sm[OFF_X + b*XS + n*8];   xv[0]=u.x; xv[1]=u.y; xv[2]=u.z; xv[3]=u.w; }
            { const float4 u = *(const float4*)&sm[OFF_X + b*XS + n*8+4]; xv[4]=u.x; xv[5]=u.y; xv[6]=u.z; xv[7]=u.w; }
            unpkrow(uXR[b*17 + n], rv);
            const float* wa = &w_gp[(mA*16+n)*20];     // uniform -> SGPRs
            const float* wb = &w_gp[(mB*16+n)*20];     // uniform -> SGPRs
            #pragma unroll
            for (int s = 0; s < 44; ++s) {
                float tz = T1S[s] ? xv[T1I[s]]*rv[T1K[s]] : -(xv[T1I[s]]*rv[T1K[s]]);
                if (SCNT[s] > 1) tz = T2S[s] ? fmaf(xv[T2I[s]], rv[T2K[s]], tz)
                                             : fmaf(-xv[T2I[s]], rv[T2K[s]], tz);
                if (SCNT[s] > 2) tz = T3S[s] ? fmaf(xv[T3I[s]], rv[T3K[s]], tz)
                                             : fmaf(-xv[T3I[s]], rv[T3K[s]], tz);
                gpA[CJ[s]] = fmaf(wa[CP[s]], tz, gpA[CJ[s]]);
                gpB[CJ[s]] = fmaf(wb[CP[s]], tz, gpB[CJ[s]]);
            }
        }
    }
    __syncthreads();   // all C reads of X/XR done before att overwrites X

    // ---------- attended = (left + b_left + gp)/sqrt(2); f32 in regs AND in X (for repack) ----------
    float attA[8], attB_[8];
    lfA[0] += b_left[mA];
    lfB[0] += b_left[mB];
    #pragma unroll
    for (int i = 0; i < 8; ++i) {
        attA[i]  = (lfA[i] + gpA[i]) * 0.70710678118654752f;
        attB_[i] = (lfB[i] + gpB[i]) * 0.70710678118654752f;
    }
    *(float4*)&sm[OFF_X + b*XS + mA*8]     = make_float4(attA[0],attA[1],attA[2],attA[3]);
    *(float4*)&sm[OFF_X + b*XS + mA*8 + 4] = make_float4(attA[4],attA[5],attA[6],attA[7]);
    *(float4*)&sm[OFF_X + b*XS + mB*8]     = make_float4(attB_[0],attB_[1],attB_[2],attB_[3]);
    *(float4*)&sm[OFF_X + b*XS + mB*8 + 4] = make_float4(attB_[4],attB_[5],attB_[6],attB_[7]);
    __syncthreads();

    // ---------- repack: att f32 (X) -> att_bf bf16 [i=wave][b=lane][n0..15] in XR region ----------
    {
        float v0 = sm[OFF_X + b*XS + 0*8 + w],  v1 = sm[OFF_X + b*XS + 1*8 + w];
        float v2 = sm[OFF_X + b*XS + 2*8 + w],  v3 = sm[OFF_X + b*XS + 3*8 + w];
        float v4 = sm[OFF_X + b*XS + 4*8 + w],  v5 = sm[OFF_X + b*XS + 5*8 + w];
        float v6 = sm[OFF_X + b*XS + 6*8 + w],  v7 = sm[OFF_X + b*XS + 7*8 + w];
        float v8 = sm[OFF_X + b*XS + 8*8 + w],  v9 = sm[OFF_X + b*XS + 9*8 + w];
        float vA = sm[OFF_X + b*XS +10*8 + w],  vB = sm[OFF_X + b*XS +11*8 + w];
        float vC = sm[OFF_X + b*XS +12*8 + w],  vD = sm[OFF_X + b*XS +13*8 + w];
        float vE = sm[OFF_X + b*XS +14*8 + w],  vF = sm[OFF_X + b*XS +15*8 + w];
        uint4* dst = (uint4*)(sm + OFF_XR) + (w*64 + b)*2;
        dst[0] = make_uint4(pk2(v0,v1), pk2(v2,v3), pk2(v4,v5), pk2(v6,v7));
        dst[1] = make_uint4(pk2(v8,v9), pk2(vA,vB), pk2(vC,vD), pk2(vE,vF));
    }
    __syncthreads();

    // ---------- phase D (MFMA): per-blade up-GEMM -> in-register silu -> per-blade down-GEMM ----------
    // wave w owns M-tile (w&3) [16 batch rows] and blade-half (w>>2) [4 blades].
    // C layout: col = lane&15, row = (lane>>4)*4 + reg  (verified). A/B k-map self-consistent (sigma trick).
    const int Mtb   = (w & 3) << 4;
    const int ihalf = w >> 2;
    const int lcol  = b & 15;
    const int lh    = b >> 4;
    const char* attBf = (const char*)(sm + OFF_XR);
    char* hB = (char*)sm;                         // X region bytes [0,16384) reused as h_bf
    f32x4 dC[4];
    #pragma unroll
    for (int q = 0; q < 4; ++q) { dC[q][0]=0.f; dC[q][1]=0.f; dC[q][2]=0.f; dC[q][3]=0.f; }

    #pragma unroll 1
    for (int ch = 0; ch < 4; ++ch) {
        const int m2 = (ch << 4) + lcol;
        // --- up: 4 blades, K=16 (upper K zero) ---
        f32x4 uC[4];
        #pragma unroll
        for (int q = 0; q < 4; ++q) {
            const int i = ihalf*4 + q;
            U4B a; a.u = make_uint4(0u,0u,0u,0u);
            if (lh < 2)
                a.u = *(const uint4*)(attBf + ((i<<6) + Mtb + lcol)*32 + (lh<<4));
            U4B wb; wb.u = wsu[((ch<<3) + i)*64 + b];
            f32x4 z; z[0]=0.f; z[1]=0.f; z[2]=0.f; z[3]=0.f;
            uC[q] = __builtin_amdgcn_mfma_f32_16x16x32_bf16(a.h, wb.h, z, 0, 0, 0);
        }
        // --- silu in C-layout (grades never cross the blade-quad boundary) ---
        const float4 aact = *(const float4*)&a_act[m2*4];
        const float4 bact = *(const float4*)&b_act[m2*4];
        const float bup = b_up[m2];
        #pragma unroll
        for (int r = 0; r < 4; ++r) {
            float h0 = uC[0][r], h1 = uC[1][r], h2 = uC[2][r], h3 = uC[3][r];
            if (ihalf == 0) {                    // blades 0..3: grade0 (scalar) + grade1
                h0 += bup;
                const float g0 = sigmoidf_(fmaf(aact.x, h0, bact.x));
                const float g1 = sigmoidf_(fmaf(aact.y, h1*h1 + h2*h2 + h3*h3, bact.y));
                h0 *= g0; h1 *= g1; h2 *= g1; h3 *= g1;
            } else {                             // blades 4..7: grade2 + grade3
                const float g2 = sigmoidf_(fmaf(aact.z, h0*h0 + h1*h1 + h2*h2, bact.z));
                const float g3 = sigmoidf_(fmaf(aact.w, h3*h3, bact.w));
                h0 *= g2; h1 *= g2; h2 *= g2; h3 *= g3;
            }
            uC[0][r]=h0; uC[1][r]=h1; uC[2][r]=h2; uC[3][r]=h3;
        }
        __syncthreads();     // prior chunk's down-reads of h_bf complete (also guards att-f32 -> h_bf clobber)
        // --- write h_bf bf16 [i][row][m2loc], dword-XOR swizzled by (row&7) ---
        #pragma unroll
        for (int q = 0; q < 4; ++q) {
            const int i = ihalf*4 + q;
            #pragma unroll
            for (int r = 0; r < 4; ++r) {
                const int br = Mtb + (lh<<2) + r;
                const int dw = (lcol >> 1) ^ (br & 7);
                *(unsigned short*)(hB + (((i<<6)+br)<<5) + (dw<<2) + ((lcol&1)<<1)) = bfb(uC[q][r]);
            }
        }
        __syncthreads();     // h_bf visible
        // --- down: 4 blades, K = this chunk's 16 m2 (upper K zero), accumulate ---
        #pragma unroll
        for (int q = 0; q < 4; ++q) {
            const int i = ihalf*4 + q;
            U4B a; a.u = make_uint4(0u,0u,0u,0u);
            if (lh < 2) {
                const unsigned* hw_ = (const unsigned*)hB + (((i<<6) + Mtb + lcol) << 3);
                const int x7 = lcol & 7;
                a.u.x = hw_[((lh<<2)+0) ^ x7];
                a.u.y = hw_[((lh<<2)+1) ^ x7];
                a.u.z = hw_[((lh<<2)+2) ^ x7];
                a.u.w = hw_[((lh<<2)+3) ^ x7];
            }
            U4B wb; wb.u = wsd[((ch<<3) + i)*64 + b];
            dC[q] = __builtin_amdgcn_mfma_f32_16x16x32_bf16(a.h, wb.h, dC[q], 0, 0, 0);
        }
    }
    __syncthreads();         // last down-reads done; X region reusable
    // --- down result -> X f32 in [b][m*8+i] layout ---
    #pragma unroll
    for (int r = 0; r < 4; ++r) {
        const int br = Mtb + (lh<<2) + r;
        *(float4*)&sm[OFF_X + br*XS + (lcol<<3) + (ihalf<<2)] =
            make_float4(dC[0][r], dC[1][r], dC[2][r], dC[3][r]);
    }
    __syncthreads();

    // ---------- epilogue: out = attended + down + b_down ----------
    {
        const float bdA = b_down[mA], bdB = b_down[mB];
        float4 a0 = *(const float4*)&sm[OFF_X + b*XS + mA*8];
        float4 a1 = *(const float4*)&sm[OFF_X + b*XS + mA*8 + 4];
        float4 b0 = *(const float4*)&sm[OFF_X + b*XS + mB*8];
        float4 b1 = *(const float4*)&sm[OFF_X + b*XS + mB*8 + 4];
        *(float4*)&sm[OFF_X + b*XS + mA*8]     = make_float4(attA[0]+a0.x+bdA, attA[1]+a0.y,
                                                             attA[2]+a0.z,     attA[3]+a0.w);
        *(float4*)&sm[OFF_X + b*XS + mA*8 + 4] = make_float4(attA[4]+a1.x, attA[5]+a1.y,
                                                             attA[6]+a1.z, attA[7]+a1.w);
        *(float4*)&sm[OFF_X + b*XS + mB*8]     = make_float4(attB_[0]+b0.x+bdB, attB_[1]+b0.y,
                                                             attB_[2]+b0.z,     attB_[3]+b0.w);
        *(float4*)&sm[OFF_X + b*XS + mB*8 + 4] = make_float4(attB_[4]+b1.x, attB_[5]+b1.y,
                                                             attB_[6]+b1.z, attB_[7]+b1.w);
    }
    __syncthreads();
    {
        float4* og = (float4*)outg + (size_t)g * 2048;
        #pragma unroll
        for (int r = 0; r < 4; ++r) {
            const int idx = r * TPB + t;
            const int el = idx >> 5, off = idx & 31;
            og[idx] = *(const float4*)&sm[OFF_X + el * XS + off * 4];
        }
    }
}

extern "C" void kernel_launch(void* const* d_in, const int* in_sizes, int n_in,
                              void* d_out, int out_size, void* d_ws, size_t ws_size,
                              hipStream_t stream) {
    const float* x       = (const float*)d_in[0];
    const float* w_right = (const float*)d_in[1];
    const float* a_norm  = (const float*)d_in[2];
    const float* w_gp    = (const float*)d_in[3];
    const float* w_left  = (const float*)d_in[4];
    const float* b_left  = (const float*)d_in[5];
    const float* w_up    = (const float*)d_in[6];
    const float* b_up    = (const float*)d_in[7];
    const float* a_act   = (const float*)d_in[8];
    const float* b_act   = (const float*)d_in[9];
    const float* w_down  = (const float*)d_in[10];
    const float* b_down  = (const float*)d_in[11];
    float* out = (float*)d_out;

    const int B = in_sizes[0] / 128;        // 65536
    const int nblocks = B / 64;             // 1024

    unsigned* wsu = (unsigned*)d_ws;        // 32 KB up B-frags
    unsigned* wsd = wsu + 8192;             // 32 KB down B-frags

    prep_pack<<<64, 256, 0, stream>>>(w_up, w_down, wsu, wsd);

    (void)hipFuncSetAttribute((const void*)mv_block_kernel,
                              hipFuncAttributeMaxDynamicSharedMemorySize, SMEM_BYTES);
    mv_block_kernel<<<nblocks, TPB, SMEM_BYTES, stream>>>(
        x, w_right, a_norm, w_gp, w_left, b_left,
        w_up, b_up, a_act, b_act, w_down, b_down,
        (const uint4*)wsu, (const uint4*)wsd, out);
}

// Round 2
// 171.624 us; speedup vs baseline: 1.2176x; 1.2176x over previous
//
#include <hip/hip_runtime.h>
#include <hip/hip_bf16.h>
#include <math.h>

#define TPB 512
#define XS    132           // f32 X region el-stride (dwords); also epilogue scratch
#define OFF_X  0            // [64][132] f32: x -> down-out scratch; bytes [0,16384) reused as h_bf
#define OFF_XR 8448         // [64][68] dwords: xr (17-stride uint4), later att_bf [8i][8p][64b] u32
#define XRU4   2112         // OFF_XR/4 : uint4 index of XR region
#define SMEM_FLOATS (8448 + 4352)       // 12800 dwords = 51200 B -> 3 blocks/CU
#define SMEM_BYTES  (SMEM_FLOATS * 4)

// ---- Cl(3,0): slot s (0..43) of the GP pair-sum (verified round 4) ----
constexpr int SCNT[44] = {1,1,1,1,1,1,1,1, 3,1,1,1, 2,2,2,2,2,2, 1,1,1, 3,
                          3, 2,2,2, 1,1,1,1,1,1, 2,2,2, 3, 1,1,1,1,1,1,1,1};
constexpr int T1I[44] = {0,0,0,0,0,0,0,0, 1,1,2,3, 2,1,1,1,1,2, 3,2,1, 1,
                         4, 4,4,5, 6,5,4,4,5,6, 5,4,4, 4, 7,7,7,7,7,7,7,7};
constexpr int T1K[44] = {0,1,2,3,4,5,6,7, 1,0,0,0, 4,4,5,2,3,3, 7,7,7, 6,
                         4, 2,1,1, 7,7,7,0,0,0, 6,6,5, 3, 7,6,5,4,3,2,1,0};
constexpr int T1S[44] = {1,1,1,1,1,1,1,1, 1,1,1,1, 0,1,1,1,1,1, 1,0,1, 1,
                         0, 1,0,0, 0,1,0,1,1,1, 0,1,0, 1, 0,0,1,0,1,0,1,1};
constexpr int T2I[44] = {0,0,0,0,0,0,0,0, 2,0,0,0, 3,3,2,2,3,3, 0,0,0, 2,
                         5, 5,6,6, 0,0,0,0,0,0, 6,6,5, 5, 0,0,0,0,0,0,0,0};
constexpr int T2K[44] = {0,0,0,0,0,0,0,0, 2,0,0,0, 5,6,6,1,1,2, 0,0,0, 5,
                         5, 3,3,2, 0,0,0,0,0,0, 5,4,4, 2, 0,0,0,0,0,0,0,0};
constexpr int T2S[44] = {1,1,1,1,1,1,1,1, 1,1,1,1, 0,0,1,0,0,0, 1,1,1, 0,
                         0, 1,1,0, 1,1,1,1,1,1, 1,0,1, 0, 1,1,1,1,1,1,1,1};
constexpr int T3I[44] = {0,0,0,0,0,0,0,0, 3,0,0,0, 0,0,0,0,0,0, 0,0,0, 3,
                         6, 0,0,0, 0,0,0,0,0,0, 0,0,0, 6, 0,0,0,0,0,0,0,0};
constexpr int T3K[44] = {0,0,0,0,0,0,0,0, 3,0,0,0, 0,0,0,0,0,0, 0,0,0, 4,
                         6, 0,0,0, 0,0,0,0,0,0, 0,0,0, 1, 0,0,0,0,0,0,0,0};
constexpr int T3S[44] = {1,1,1,1,1,1,1,1, 1,1,1,1, 1,1,1,1,1,1, 1,1,1, 1,
                         0, 1,1,1, 1,1,1,1,1,1, 1,1,1, 1, 1,1,1,1,1,1,1,1};
constexpr int CP[44] = {
    0, 1,1,1, 2,2,2, 3,
    4, 5,5,5, 6,6,6, 7,7,7, 8,8,8, 9,
    10, 11,11,11, 12,12,12, 13,13,13, 14,14,14, 15,
    16, 17,17,17, 18,18,18, 19};
constexpr int CJ[44] = {
    0, 1,2,3, 4,5,6, 7,
    0, 1,2,3, 1,2,3, 4,5,6, 4,5,6, 7,
    0, 1,2,3, 1,2,3, 4,5,6, 4,5,6, 7,
    0, 1,2,3, 4,5,6, 7};

typedef __attribute__((ext_vector_type(8))) short bf16x8;
typedef __attribute__((ext_vector_type(4))) float f32x4;
union U4B { uint4 u; bf16x8 h; };

__device__ __forceinline__ float sigmoidf_(float v) {
    return __builtin_amdgcn_rcpf(1.0f + __expf(-v));
}
__device__ __forceinline__ unsigned pk2(float lo, float hi) {
    __hip_bfloat162 h = __float22bfloat162_rn(make_float2(lo, hi));
    return *reinterpret_cast<unsigned*>(&h);
}
__device__ __forceinline__ unsigned short bfb(float v) {
    __hip_bfloat16 h = __float2bfloat16(v);
    return *reinterpret_cast<unsigned short*>(&h);
}
__device__ __forceinline__ uint4 pkrow(const float* v) {
    return make_uint4(pk2(v[0],v[1]), pk2(v[2],v[3]), pk2(v[4],v[5]), pk2(v[6],v[7]));
}
__device__ __forceinline__ void unpkrow(uint4 u, float* v) {
    v[0]=__uint_as_float(u.x<<16); v[1]=__uint_as_float(u.x&0xffff0000u);
    v[2]=__uint_as_float(u.y<<16); v[3]=__uint_as_float(u.y&0xffff0000u);
    v[4]=__uint_as_float(u.z<<16); v[5]=__uint_as_float(u.z&0xffff0000u);
    v[6]=__uint_as_float(u.w<<16); v[7]=__uint_as_float(u.w&0xffff0000u);
}

// ---- prep: pack w_up / w_down into B-fragment-ordered bf16 pairs ----
// frag f = ch*8 + i ; lane l ; dword jp ; k-slot map: k0 = 8*(l>>4) + 2*jp  (k>=16 -> 0)
// up:   B[k=n][col=m2=ch*16+(l&15)]  = w_up[m2][n][g(i)]
// down: B[k=m2loc][col=m=(l&15)]     = w_down[m][ch*16+m2loc][g(i)]
__global__ void prep_pack(const float* __restrict__ w_up,
                          const float* __restrict__ w_down,
                          unsigned* __restrict__ wsu,
                          unsigned* __restrict__ wsd)
{
    const int t = blockIdx.x * 256 + threadIdx.x;       // 0..16383
    const int d  = t & 8191;
    const int f  = d >> 8;                              // 0..31
    const int rj = d & 255;
    const int l  = rj >> 2, jp = rj & 3;
    const int ch = f >> 3, i = f & 7;
    const int g  = (i == 0) ? 0 : (i <= 3 ? 1 : (i <= 6 ? 2 : 3));
    const int k0 = ((l >> 4) << 3) + (jp << 1);
    if (t < 8192) {
        const int m2 = (ch << 4) + (l & 15);
        const float v0 = (k0     < 16) ? w_up[(m2*16 + k0    )*4 + g] : 0.f;
        const float v1 = (k0 + 1 < 16) ? w_up[(m2*16 + k0 + 1)*4 + g] : 0.f;
        wsu[d] = pk2(v0, v1);
    } else {
        const int m = l & 15;
        const float v0 = (k0     < 16) ? w_down[(m*64 + (ch<<4) + k0    )*4 + g] : 0.f;
        const float v1 = (k0 + 1 < 16) ? w_down[(m*64 + (ch<<4) + k0 + 1)*4 + g] : 0.f;
        wsd[d] = pk2(v0, v1);
    }
}

__global__ __launch_bounds__(TPB, 4)
void mv_block_kernel(const float* __restrict__ xg,
                     const float* __restrict__ w_right,
                     const float* __restrict__ a_norm,
                     const float* __restrict__ w_gp,
                     const float* __restrict__ w_left,
                     const float* __restrict__ b_left,
                     const float* __restrict__ w_up,
                     const float* __restrict__ b_up,
                     const float* __restrict__ a_act,
                     const float* __restrict__ b_act,
                     const float* __restrict__ w_down,
                     const float* __restrict__ b_down,
                     const uint4* __restrict__ wsu,
                     const uint4* __restrict__ wsd,
                     float* __restrict__ outg)
{
    extern __shared__ float sm[];
    uint4* uXR = ((uint4*)sm) + XRU4;
    const int t = threadIdx.x;
    const int b = t & 63;                                   // lane = batch element (A-C) / MFMA lane (D)
    const int w = __builtin_amdgcn_readfirstlane(t >> 6);   // wave 0..7 (uniform)
    const int mA = 2*w, mB = 2*w + 1;                       // adjacent channel pair -> att pk2 is one A-dword
    const int g = blockIdx.x;

    // ---------- stage x (coalesced, f32) ----------
    {
        const float4* xs = (const float4*)xg + (size_t)g * 2048;
        #pragma unroll
        for (int r = 0; r < 4; ++r) {
            const int idx = r * TPB + t;
            const float4 v = xs[idx];
            const int el = idx >> 5, off = idx & 31;
            *(float4*)&sm[OFF_X + el * XS + off * 4] = v;
        }
    }
    __syncthreads();

    // ---------- phase A: right-linear + left-linear (2 channels, weights in SGPRs) ----------
    float xrA[8] = {0,0,0,0,0,0,0,0}, xrB[8] = {0,0,0,0,0,0,0,0};
    float lfA[8] = {0,0,0,0,0,0,0,0}, lfB[8] = {0,0,0,0,0,0,0,0};
    {
        const float* sx = &sm[OFF_X + b * XS];
        #pragma unroll 1
        for (int n = 0; n < 16; ++n) {
            const float4 xa = *(const float4*)&sx[n*8];
            const float4 xb = *(const float4*)&sx[n*8+4];
            const float4 wa = *(const float4*)&w_right[(mA*16+n)*4];
            const float4 wb = *(const float4*)&w_right[(mB*16+n)*4];
            const float4 va = *(const float4*)&w_left [(mA*16+n)*4];
            const float4 vb = *(const float4*)&w_left [(mB*16+n)*4];
            xrA[0]+=xa.x*wa.x; xrA[1]+=xa.y*wa.y; xrA[2]+=xa.z*wa.y; xrA[3]+=xa.w*wa.y;
            xrA[4]+=xb.x*wa.z; xrA[5]+=xb.y*wa.z; xrA[6]+=xb.z*wa.z; xrA[7]+=xb.w*wa.w;
            xrB[0]+=xa.x*wb.x; xrB[1]+=xa.y*wb.y; xrB[2]+=xa.z*wb.y; xrB[3]+=xa.w*wb.y;
            xrB[4]+=xb.x*wb.z; xrB[5]+=xb.y*wb.z; xrB[6]+=xb.z*wb.z; xrB[7]+=xb.w*wb.w;
            lfA[0]+=xa.x*va.x; lfA[1]+=xa.y*va.y; lfA[2]+=xa.z*va.y; lfA[3]+=xa.w*va.y;
            lfA[4]+=xb.x*va.z; lfA[5]+=xb.y*va.z; lfA[6]+=xb.z*va.z; lfA[7]+=xb.w*va.w;
            lfB[0]+=xa.x*vb.x; lfB[1]+=xa.y*vb.y; lfB[2]+=xa.z*vb.y; lfB[3]+=xa.w*vb.y;
            lfB[4]+=xb.x*vb.z; lfB[5]+=xb.y*vb.z; lfB[6]+=xb.z*vb.z; lfB[7]+=xb.w*vb.w;
        }
    }

    // ---------- phase B: gated per-grade normalization ----------
    #pragma unroll
    for (int q = 0; q < 2; ++q) {
        float* xr = q ? xrB : xrA;
        const int m = q ? mB : mA;
        const float q0 = xr[0]*xr[0];
        const float q1 = xr[1]*xr[1] + xr[2]*xr[2] + xr[3]*xr[3];
        const float q2 = xr[4]*xr[4] + xr[5]*xr[5] + xr[6]*xr[6];
        const float q3 = xr[7]*xr[7];
        const float4 an = *(const float4*)&a_norm[m*4];
        const float i0 = __builtin_amdgcn_rcpf(sigmoidf_(an.x)*(sqrtf(q0)-1.0f)+1.0f + 1e-6f);
        const float i1 = __builtin_amdgcn_rcpf(sigmoidf_(an.y)*(sqrtf(q1)-1.0f)+1.0f + 1e-6f);
        const float i2 = __builtin_amdgcn_rcpf(sigmoidf_(an.z)*(sqrtf(q2)-1.0f)+1.0f + 1e-6f);
        const float i3 = __builtin_amdgcn_rcpf(sigmoidf_(an.w)*(sqrtf(q3)-1.0f)+1.0f + 1e-6f);
        xr[0]*=i0; xr[1]*=i1; xr[2]*=i1; xr[3]*=i1;
        xr[4]*=i2; xr[5]*=i2; xr[6]*=i2; xr[7]*=i3;
    }
    uXR[b*17 + mA] = pkrow(xrA);     // xr -> bf16 LDS (1 uint4 per channel)
    uXR[b*17 + mB] = pkrow(xrB);
    __syncthreads();

    // ---------- phase C: direct GP; pair products shared across the wave's 2 channels ----------
    float gpA[8] = {0,0,0,0,0,0,0,0}, gpB[8] = {0,0,0,0,0,0,0,0};
    {
        #pragma unroll 1
        for (int n = 0; n < 16; ++n) {
            float xv[8], rv[8];
            { const float4 u = *(const float4*)&sm[OFF_X + b*XS + n*8];   xv[0]=u.x; xv[1]=u.y; xv[2]=u.z; xv[3]=u.w; }
            { const float4 u = *(const float4*)&sm[OFF_X + b*XS + n*8+4]; xv[4]=u.x; xv[5]=u.y; xv[6]=u.z; xv[7]=u.w; }
            unpkrow(uXR[b*17 + n], rv);
            const float* wa = &w_gp[(mA*16+n)*20];     // uniform -> SGPRs
            const float* wb = &w_gp[(mB*16+n)*20];     // uniform -> SGPRs
            #pragma unroll
            for (int s = 0; s < 44; ++s) {
                float tz = T1S[s] ? xv[T1I[s]]*rv[T1K[s]] : -(xv[T1I[s]]*rv[T1K[s]]);
                if (SCNT[s] > 1) tz = T2S[s] ? fmaf(xv[T2I[s]], rv[T2K[s]], tz)
                                             : fmaf(-xv[T2I[s]], rv[T2K[s]], tz);
                if (SCNT[s] > 2) tz = T3S[s] ? fmaf(xv[T3I[s]], rv[T3K[s]], tz)
                                             : fmaf(-xv[T3I[s]], rv[T3K[s]], tz);
                gpA[CJ[s]] = fmaf(wa[CP[s]], tz, gpA[CJ[s]]);
                gpB[CJ[s]] = fmaf(wb[CP[s]], tz, gpB[CJ[s]]);
            }
        }
    }
    __syncthreads();   // all C reads of X/XR done before att_bf overwrites XR

    // ---------- attended = (left + b_left + gp)/sqrt(2); regs only ----------
    float attA[8], attB_[8];
    lfA[0] += b_left[mA];
    lfB[0] += b_left[mB];
    #pragma unroll
    for (int i = 0; i < 8; ++i) {
        attA[i]  = (lfA[i] + gpA[i]) * 0.70710678118654752f;
        attB_[i] = (lfB[i] + gpB[i]) * 0.70710678118654752f;
    }
    // direct reg -> att_bf [i][p=w][b] u32 (bf16 pair = channels 2w,2w+1); conflict-free
    {
        unsigned* attW = (unsigned*)(sm + OFF_XR);
        #pragma unroll
        for (int i = 0; i < 8; ++i)
            attW[(i<<9) + (w<<6) + b] = pk2(attA[i], attB_[i]);
    }
    __syncthreads();

    // ---------- phase D (MFMA): per-blade up-GEMM -> in-register silu -> per-blade down-GEMM ----------
    // wave w owns M-tile (w&3) [16 batch rows] and blade-half (w>>2) [4 blades].
    // C layout: col = lane&15, row = (lane>>4)*4 + reg (verified r1). A/B k-map self-consistent (sigma).
    const int Mtb   = (w & 3) << 4;
    const int ihalf = w >> 2;
    const int lcol  = b & 15;
    const int lh    = b >> 4;
    char* hB = (char*)sm;                         // X region bytes [0,16384) reused as h_bf
    f32x4 dC[4];
    #pragma unroll
    for (int q = 0; q < 4; ++q) { dC[q][0]=0.f; dC[q][1]=0.f; dC[q][2]=0.f; dC[q][3]=0.f; }

    #pragma unroll 1
    for (int ch = 0; ch < 4; ++ch) {
        const int m2 = (ch << 4) + lcol;
        // --- up: 4 blades, K=16 (upper K zero) ---
        f32x4 uC[4];
        #pragma unroll
        for (int q = 0; q < 4; ++q) {
            const int i = ihalf*4 + q;
            U4B a; a.u = make_uint4(0u,0u,0u,0u);
            if (lh < 2) {   // k-slots >=16 multiply zero B rows; skip their loads
                const unsigned* rowp = (const unsigned*)(sm + OFF_XR) + (i<<9) + Mtb + lcol;
                a.u.x = rowp[(4*lh+0)<<6];
                a.u.y = rowp[(4*lh+1)<<6];
                a.u.z = rowp[(4*lh+2)<<6];
                a.u.w = rowp[(4*lh+3)<<6];
            }
            U4B wb; wb.u = wsu[((ch<<3) + i)*64 + b];
            f32x4 z; z[0]=0.f; z[1]=0.f; z[2]=0.f; z[3]=0.f;
            uC[q] = __builtin_amdgcn_mfma_f32_16x16x32_bf16(a.h, wb.h, z, 0, 0, 0);
        }
        // --- silu in C-layout (grades never cross the blade-quad boundary) ---
        const float4 aact = *(const float4*)&a_act[m2*4];
        const float4 bact = *(const float4*)&b_act[m2*4];
        const float bup = b_up[m2];
        #pragma unroll
        for (int r = 0; r < 4; ++r) {
            float h0 = uC[0][r], h1 = uC[1][r], h2 = uC[2][r], h3 = uC[3][r];
            if (ihalf == 0) {                    // blades 0..3: grade0 (scalar) + grade1
                h0 += bup;
                const float g0 = sigmoidf_(fmaf(aact.x, h0, bact.x));
                const float g1 = sigmoidf_(fmaf(aact.y, h1*h1 + h2*h2 + h3*h3, bact.y));
                h0 *= g0; h1 *= g1; h2 *= g1; h3 *= g1;
            } else {                             // blades 4..7: grade2 + grade3
                const float g2 = sigmoidf_(fmaf(aact.z, h0*h0 + h1*h1 + h2*h2, bact.z));
                const float g3 = sigmoidf_(fmaf(aact.w, h3*h3, bact.w));
                h0 *= g2; h1 *= g2; h2 *= g2; h3 *= g3;
            }
            uC[0][r]=h0; uC[1][r]=h1; uC[2][r]=h2; uC[3][r]=h3;
        }
        __syncthreads();     // prior chunk's down-reads of h_bf complete (guards X clobber for ch=0)
        // --- write h_bf bf16 [i][row][m2loc], dword-XOR swizzled by (row&7) ---
        #pragma unroll
        for (int q = 0; q < 4; ++q) {
            const int i = ihalf*4 + q;
            #pragma unroll
            for (int r = 0; r < 4; ++r) {
                const int br = Mtb + (lh<<2) + r;
                const int dw = (lcol >> 1) ^ (br & 7);
                *(unsigned short*)(hB + (((i<<6)+br)<<5) + (dw<<2) + ((lcol&1)<<1)) = bfb(uC[q][r]);
            }
        }
        __syncthreads();     // h_bf visible
        // --- down: 4 blades, K = this chunk's 16 m2 (upper K zero), accumulate ---
        #pragma unroll
        for (int q = 0; q < 4; ++q) {
            const int i = ihalf*4 + q;
            U4B a; a.u = make_uint4(0u,0u,0u,0u);
            if (lh < 2) {
                const unsigned* hw_ = (const unsigned*)hB + (((i<<6) + Mtb + lcol) << 3);
                const int x7 = lcol & 7;
                a.u.x = hw_[((lh<<2)+0) ^ x7];
                a.u.y = hw_[((lh<<2)+1) ^ x7];
                a.u.z = hw_[((lh<<2)+2) ^ x7];
                a.u.w = hw_[((lh<<2)+3) ^ x7];
            }
            U4B wb; wb.u = wsd[((ch<<3) + i)*64 + b];
            dC[q] = __builtin_amdgcn_mfma_f32_16x16x32_bf16(a.h, wb.h, dC[q], 0, 0, 0);
        }
    }
    __syncthreads();         // last down-reads done; X region reusable
    // --- down result -> X f32 in [b][m*8+i] layout ---
    #pragma unroll
    for (int r = 0; r < 4; ++r) {
        const int br = Mtb + (lh<<2) + r;
        *(float4*)&sm[OFF_X + br*XS + (lcol<<3) + (ihalf<<2)] =
            make_float4(dC[0][r], dC[1][r], dC[2][r], dC[3][r]);
    }
    __syncthreads();

    // ---------- epilogue: out = attended + down + b_down ----------
    {
        const float bdA = b_down[mA], bdB = b_down[mB];
        float4 a0 = *(const float4*)&sm[OFF_X + b*XS + mA*8];
        float4 a1 = *(const float4*)&sm[OFF_X + b*XS + mA*8 + 4];
        float4 b0 = *(const float4*)&sm[OFF_X + b*XS + mB*8];
        float4 b1 = *(const float4*)&sm[OFF_X + b*XS + mB*8 + 4];
        *(float4*)&sm[OFF_X + b*XS + mA*8]     = make_float4(attA[0]+a0.x+bdA, attA[1]+a0.y,
                                                             attA[2]+a0.z,     attA[3]+a0.w);
        *(float4*)&sm[OFF_X + b*XS + mA*8 + 4] = make_float4(attA[4]+a1.x, attA[5]+a1.y,
                                                             attA[6]+a1.z, attA[7]+a1.w);
        *(float4*)&sm[OFF_X + b*XS + mB*8]     = make_float4(attB_[0]+b0.x+bdB, attB_[1]+b0.y,
                                                             attB_[2]+b0.z,     attB_[3]+b0.w);
        *(float4*)&sm[OFF_X + b*XS + mB*8 + 4] = make_float4(attB_[4]+b1.x, attB_[5]+b1.y,
                                                             attB_[6]+b1.z, attB_[7]+b1.w);
    }
    __syncthreads();
    {
        float4* og = (float4*)outg + (size_t)g * 2048;
        #pragma unroll
        for (int r = 0; r < 4; ++r) {
            const int idx = r * TPB + t;
            const int el = idx >> 5, off = idx & 31;
            og[idx] = *(const float4*)&sm[OFF_X + el * XS + off * 4];
        }
    }
}

extern "C" void kernel_launch(void* const* d_in, const int* in_sizes, int n_in,
                              void* d_out, int out_size, void* d_ws, size_t ws_size,
                              hipStream_t stream) {
    const float* x       = (const float*)d_in[0];
    const float* w_right = (const float*)d_in[1];
    const float* a_norm  = (const float*)d_in[2];
    const float* w_gp    = (const float*)d_in[3];
    const float* w_left  = (const float*)d_in[4];
    const float* b_left  = (const float*)d_in[5];
    const float* w_up    = (const float*)d_in[6];
    const float* b_up    = (const float*)d_in[7];
    const float* a_act   = (const float*)d_in[8];
    const float* b_act   = (const float*)d_in[9];
    const float* w_down  = (const float*)d_in[10];
    const float* b_down  = (const float*)d_in[11];
    float* out = (float*)d_out;

    const int B = in_sizes[0] / 128;        // 65536
    const int nblocks = B / 64;             // 1024

    unsigned* wsu = (unsigned*)d_ws;        // 32 KB up B-frags
    unsigned* wsd = wsu + 8192;             // 32 KB down B-frags

    prep_pack<<<64, 256, 0, stream>>>(w_up, w_down, wsu, wsd);

    (void)hipFuncSetAttribute((const void*)mv_block_kernel,
                              hipFuncAttributeMaxDynamicSharedMemorySize, SMEM_BYTES);
    mv_block_kernel<<<nblocks, TPB, SMEM_BYTES, stream>>>(
        x, w_right, a_norm, w_gp, w_left, b_left,
        w_up, b_up, a_act, b_act, w_down, b_down,
        (const uint4*)wsu, (const uint4*)wsd, out);
}